// Round 9
// baseline (583.663 us; speedup 1.0000x reference)
//
#include <hip/hip_runtime.h>
#include <math.h>

// CapsuleLayer dynamic routing, MI355X.
// B=4096, L=200, Din=Dout=64, K=8, 3 iterations.
//
// R8 -> R9: the wall was the LDS/DS PIPE (1 per CU, shared by 4 SIMDs):
// ~220K DS-cycles/CU per route (broadcast ds_reads + ds_bpermute shuffles)
// ~= the observed ~90us real route time. This round removes the DS pipe
// from the hot path entirely:
//   - wave-per-batch route kernel: NO __shared__, NO __syncthreads
//   - W read via wave-uniform pointer (readfirstlane) -> s_load (SMEM pipe)
//   - cross-lane broadcasts via __builtin_amdgcn_readlane (VALU pipe)
//   - delta: lane-owns-row, float4 row reads (L2-hot), readlane hs bcast
// Only DS ops left: 48 shfl_xor per wave for the squash reduction.
//
// ws layout (floats):
//   Bc[1600] | St[4096] | W_T[B*L*K = 6,553,600  layout (b,l,k)] |
//   partial[B*K*L = 6,553,600]
// partial2 [16*K*L] lives in d_out (fully overwritten by the final pass).

#define B_SZ  4096
#define L_SZ  200
#define DK    64
#define K_SZ  8

__device__ __forceinline__ float rl(float x, int i) {
    return __int_as_float(__builtin_amdgcn_readlane(__float_as_int(x), i));
}

// ---------------------------- init: copy Bc + transpose S into St
__global__ __launch_bounds__(256) void k_init(const float* __restrict__ Bm,
                                              const float* __restrict__ S,
                                              float* __restrict__ Bc,
                                              float* __restrict__ St) {
    int i = blockIdx.x * 256 + threadIdx.x;
    if (i < K_SZ * L_SZ) Bc[i] = Bm[i];
    int j = i - K_SZ * L_SZ;
    if (j >= 0 && j < DK * DK) {
        int o = j >> 6, ii = j & 63;
        St[j] = S[ii * DK + o];        // St[o][i] = S[i][o]
    }
}

// ---------------- softmax: W_T[b][l][k] = normalized masked softmax of Bc
// grid 4096 x 256; warp k owns row k; transposed coalesced store.
__global__ __launch_bounds__(256) void k_soft(const int* __restrict__ seq_len,
                                              const float* __restrict__ Bc,
                                              float* __restrict__ Wt_g) {
    __shared__ float W_s[K_SZ][L_SZ];
    int t = threadIdx.x, b = blockIdx.x;
    int k = t >> 5, g = t & 31;
    int sl = seq_len[b];

    const float* bk = Bc + k * L_SZ;
    float m = -3.4e38f;
    for (int l = g; l < sl; l += 32) m = fmaxf(m, bk[l]);
    #pragma unroll
    for (int s = 16; s; s >>= 1) m = fmaxf(m, __shfl_xor(m, s, 32));
    float sum = 0.f;
    for (int l = g; l < L_SZ; l += 32) {
        float e = (l < sl) ? __expf(bk[l] - m) : 0.f;
        sum += e;
        W_s[k][l] = e;
    }
    #pragma unroll
    for (int s = 16; s; s >>= 1) sum += __shfl_xor(sum, s, 32);
    float rinv = 1.0f / sum;
    for (int l = g; l < L_SZ; l += 32) W_s[k][l] *= rinv;
    __syncthreads();

    float* dst = Wt_g + (long)b * (K_SZ * L_SZ);
    for (int j = t; j < K_SZ * L_SZ; j += 256)
        dst[j] = W_s[j & 7][j >> 3];   // dst[l*8+k] = W[k][l]
}

// ---------------- route: one WAVE per batch, no LDS, no barriers.
// grid 1024 x 256 (4 waves = 4 batches per block).
// WRITE_OUT=1 (final iter): write squashed high, stop.
template<int WRITE_OUT>
__global__ __launch_bounds__(256, 4) void k_route3(const float* __restrict__ lc_g,
                                                   const float* __restrict__ Wt_g,
                                                   const float* __restrict__ S_g,
                                                   const float* __restrict__ St_g,
                                                   float* __restrict__ partial,
                                                   float* __restrict__ out) {
    int t = threadIdx.x;
    int lam = t & 63;
    int wv = __builtin_amdgcn_readfirstlane(t >> 6);   // wave-uniform by construction
    int b = blockIdx.x * 4 + wv;                       // uniform -> scalar addressing
    const float* __restrict__ lcb = lc_g + (long)b * (L_SZ * DK);
    const float* __restrict__ wt  = Wt_g + (long)b * (K_SZ * L_SZ);

    // 1. hp[k][lam] = sum_l W[k][l] * lc[l][lam]
    //    W via uniform float4 loads (s_load_dwordx4 expected); lc coalesced b32.
    float acc[K_SZ] = {0.f, 0.f, 0.f, 0.f, 0.f, 0.f, 0.f, 0.f};
    {
        const float* lp = lcb + lam;
        #pragma unroll 4
        for (int l = 0; l < L_SZ; ++l) {
            float v = lp[l * DK];
            float4 wa = *(const float4*)(wt + l * K_SZ);
            float4 wb = *(const float4*)(wt + l * K_SZ + 4);
            acc[0] = fmaf(wa.x, v, acc[0]);
            acc[1] = fmaf(wa.y, v, acc[1]);
            acc[2] = fmaf(wa.z, v, acc[2]);
            acc[3] = fmaf(wa.w, v, acc[3]);
            acc[4] = fmaf(wb.x, v, acc[4]);
            acc[5] = fmaf(wb.y, v, acc[5]);
            acc[6] = fmaf(wb.z, v, acc[6]);
            acc[7] = fmaf(wb.w, v, acc[7]);
        }
    }

    // 2. high[k][lam] = sum_i hp[k][i] * S[i][lam]   (readlane broadcast of hp)
    float h[K_SZ] = {0.f, 0.f, 0.f, 0.f, 0.f, 0.f, 0.f, 0.f};
    {
        const float* sp = S_g + lam;
        for (int i = 0; i < DK; ++i) {          // uniform i -> readlane w/ SGPR idx
            float v = sp[i * DK];               // coalesced, L1-hot
            #pragma unroll
            for (int k = 0; k < K_SZ; ++k)
                h[k] = fmaf(rl(acc[k], i), v, h[k]);
        }
    }

    // 3. squash (only DS ops in the kernel: 48 shfl_xor)
    #pragma unroll
    for (int k = 0; k < K_SZ; ++k) {
        float nn = h[k] * h[k];
        #pragma unroll
        for (int s = 1; s < 64; s <<= 1) nn += __shfl_xor(nn, s, 64);
        float sc = nn / ((1.0f + nn) * sqrtf(nn + 1e-9f));
        h[k] *= sc;
    }

    if (WRITE_OUT) {
        float* ob = out + (long)b * (K_SZ * DK) + lam;
        #pragma unroll
        for (int k = 0; k < K_SZ; ++k) ob[k * DK] = h[k];   // coalesced
        return;
    }

    // 4. hs[k][lam] = sum_o high[k][o] * St[o][lam]
    float hs[K_SZ] = {0.f, 0.f, 0.f, 0.f, 0.f, 0.f, 0.f, 0.f};
    {
        const float* sp = St_g + lam;
        for (int o = 0; o < DK; ++o) {
            float v = sp[o * DK];               // coalesced, L1-hot
            #pragma unroll
            for (int k = 0; k < K_SZ; ++k)
                hs[k] = fmaf(rl(h[k], o), v, hs[k]);
        }
    }

    // 5. delta: lane owns rows lam, lam+64, lam+128, (lam+192 if lam<8).
    //    partial[k][l] = sum_i hs[k][i] * lc[l][i]; hs broadcast via readlane.
    {
        int live3 = (lam < 8);
        int r3 = live3 ? (192 + lam) : 0;       // clamped addr, store masked
        const float4* p0 = (const float4*)(lcb + (long)lam * DK);
        const float4* p1 = (const float4*)(lcb + (long)(64 + lam) * DK);
        const float4* p2 = (const float4*)(lcb + (long)(128 + lam) * DK);
        const float4* p3 = (const float4*)(lcb + (long)r3 * DK);
        float a0[K_SZ] = {}, a1[K_SZ] = {}, a2[K_SZ] = {}, a3[K_SZ] = {};
        for (int i4 = 0; i4 < 16; ++i4) {       // uniform i4
            float4 v0 = p0[i4], v1 = p1[i4], v2 = p2[i4], v3 = p3[i4];
            #pragma unroll
            for (int k = 0; k < K_SZ; ++k) {
                float s0 = rl(hs[k], 4 * i4 + 0);
                float s1 = rl(hs[k], 4 * i4 + 1);
                float s2 = rl(hs[k], 4 * i4 + 2);
                float s3 = rl(hs[k], 4 * i4 + 3);
                a0[k] = fmaf(s0, v0.x, fmaf(s1, v0.y, fmaf(s2, v0.z, fmaf(s3, v0.w, a0[k]))));
                a1[k] = fmaf(s0, v1.x, fmaf(s1, v1.y, fmaf(s2, v1.z, fmaf(s3, v1.w, a1[k]))));
                a2[k] = fmaf(s0, v2.x, fmaf(s1, v2.y, fmaf(s2, v2.z, fmaf(s3, v2.w, a2[k]))));
                a3[k] = fmaf(s0, v3.x, fmaf(s1, v3.y, fmaf(s2, v3.z, fmaf(s3, v3.w, a3[k]))));
            }
        }
        float* pb = partial + (long)b * (K_SZ * L_SZ);
        #pragma unroll
        for (int k = 0; k < K_SZ; ++k) {
            pb[k * L_SZ + lam]       = a0[k];   // coalesced over lam
            pb[k * L_SZ + 64 + lam]  = a1[k];
            pb[k * L_SZ + 128 + lam] = a2[k];
            if (live3) pb[k * L_SZ + 192 + lam] = a3[k];
        }
    }
}

// --------------------------- deterministic two-stage reduce of partials
__global__ __launch_bounds__(256) void k_reduceA(const float* __restrict__ partial,
                                                 float* __restrict__ partial2) {
    __shared__ float red[256];
    int x = blockIdx.x % 50;       // 32-output group
    int y = blockIdx.x / 50;       // 256-batch chunk
    int t = threadIdx.x;
    int i = x * 32 + (t & 31);
    int sub = t >> 5;
    float s = 0.f;
    for (int p = y * 256 + sub; p < (y + 1) * 256; p += 8)
        s += partial[(long)p * (K_SZ * L_SZ) + i];
    red[t] = s;
    __syncthreads();
    for (int step = 4; step >= 1; step >>= 1) {
        if (sub < step) red[t] += red[t + step * 32];
        __syncthreads();
    }
    if (sub == 0) partial2[y * (K_SZ * L_SZ) + i] = red[t];
}

__global__ __launch_bounds__(256) void k_reduceB(const float* __restrict__ partial2,
                                                 float* __restrict__ Bc) {
    int i = blockIdx.x * 256 + threadIdx.x;
    if (i < K_SZ * L_SZ) {
        float s = 0.f;
        #pragma unroll
        for (int y = 0; y < 16; ++y) s += partial2[y * (K_SZ * L_SZ) + i];
        Bc[i] += s;
    }
}

extern "C" void kernel_launch(void* const* d_in, const int* in_sizes, int n_in,
                              void* d_out, int out_size, void* d_ws, size_t ws_size,
                              hipStream_t stream) {
    const float* lc = (const float*)d_in[0];   // [4096,200,64]
    const int*   sl = (const int*)d_in[1];     // [4096,1]
    const float* Bm = (const float*)d_in[2];   // [1,8,200]
    const float* S  = (const float*)d_in[3];   // [64,64]
    float* out = (float*)d_out;                // [4096,8,64]
    float* ws  = (float*)d_ws;

    float* Bc      = ws;                       // 1,600
    float* St      = Bc + 1600;                // 4,096
    float* Wt      = St + 4096;                // 6,553,600   (b,l,k)
    float* partial = Wt + (long)B_SZ * K_SZ * L_SZ;   // 6,553,600
    float* p2      = out;                      // scratch: overwritten by final pass

    k_init<<<23, 256, 0, stream>>>(Bm, S, Bc, St);

    k_soft     <<<B_SZ, 256, 0, stream>>>(sl, Bc, Wt);
    k_route3<0><<<B_SZ / 4, 256, 0, stream>>>(lc, Wt, S, St, partial, out);
    k_reduceA  <<<800, 256, 0, stream>>>(partial, p2);
    k_reduceB  <<<7, 256, 0, stream>>>(p2, Bc);

    k_soft     <<<B_SZ, 256, 0, stream>>>(sl, Bc, Wt);
    k_route3<0><<<B_SZ / 4, 256, 0, stream>>>(lc, Wt, S, St, partial, out);
    k_reduceA  <<<800, 256, 0, stream>>>(partial, p2);
    k_reduceB  <<<7, 256, 0, stream>>>(p2, Bc);

    k_soft     <<<B_SZ, 256, 0, stream>>>(sl, Bc, Wt);
    k_route3<1><<<B_SZ / 4, 256, 0, stream>>>(lc, Wt, S, St, partial, out);
}

// Round 11
// 328.919 us; speedup vs baseline: 1.7745x; 1.7745x over previous
//
#include <hip/hip_runtime.h>
#include <math.h>

// CapsuleLayer dynamic routing, MI355X.
// B=4096, L=200, Din=Dout=64, K=8, 3 iterations.
//
// R9 -> R10: R8 was DS-pipe-bound (~90us/route); R9 (wave-per-batch, no LDS)
// was HBM-overfetch-bound (790MB fetch @ 2.9TB/s = 284us exactly). R10
// combines block-per-batch locality with all-VALU/SALU broadcasts:
//   - softmax dedup: Bc is shared across batches; W depends only on
//     sl in {1..200} -> precompute Wt[200][L][K] (1.28MB, L2-resident).
//   - hp: wave-uniform row -> W row via s_load_dwordx8 (SMEM pipe) +
//     v_fmac with SGPR operand; lc coalesced 256B/wave. Zero DS.
//   - delta: readlane hs broadcasts (VALU), rows L1/L2-hot from hp pass.
//   - tiny projections: LDS broadcast loops (small, ~5us total).
// (R10 bench was lost to an UnresponsiveContainer infra failure; this is an
//  unchanged resubmit to obtain the measurement.)
//
// ws layout (floats):
//   Bc[1600] | St[4096] | Wt[200*1600 = 320,000  layout (s,l,k)] |
//   partial[B*K*L = 6,553,600]
// partial2 [16*K*L] lives in d_out (fully overwritten by the final pass).

#define B_SZ  4096
#define L_SZ  200
#define DK    64
#define K_SZ  8

__device__ __forceinline__ float rl(float x, int i) {
    return __int_as_float(__builtin_amdgcn_readlane(__float_as_int(x), i));
}

// ---------------------------- init: copy Bc + transpose S into St
__global__ __launch_bounds__(256) void k_init(const float* __restrict__ Bm,
                                              const float* __restrict__ S,
                                              float* __restrict__ Bc,
                                              float* __restrict__ St) {
    int i = blockIdx.x * 256 + threadIdx.x;
    if (i < K_SZ * L_SZ) Bc[i] = Bm[i];
    int j = i - K_SZ * L_SZ;
    if (j >= 0 && j < DK * DK) {
        int o = j >> 6, ii = j & 63;
        St[j] = S[ii * DK + o];        // St[o][i] = S[i][o]
    }
}

// ---------------- softmax dedup: Wt[s-1][l][k] for every possible sl=s.
// grid 200 x 256; warp k owns logit row k; masked to l<s, zero-filled to L.
__global__ __launch_bounds__(256) void k_soft(const float* __restrict__ Bc,
                                              float* __restrict__ Wt_g) {
    __shared__ float W_s[K_SZ][L_SZ];
    int t = threadIdx.x;
    int s = blockIdx.x + 1;            // sl value this block covers
    int k = t >> 5, g = t & 31;

    const float* bk = Bc + k * L_SZ;
    float m = -3.4e38f;
    for (int l = g; l < s; l += 32) m = fmaxf(m, bk[l]);
    #pragma unroll
    for (int st = 16; st; st >>= 1) m = fmaxf(m, __shfl_xor(m, st, 32));
    float sum = 0.f;
    for (int l = g; l < L_SZ; l += 32) {
        float e = (l < s) ? __expf(bk[l] - m) : 0.f;
        sum += e;
        W_s[k][l] = e;
    }
    #pragma unroll
    for (int st = 16; st; st >>= 1) sum += __shfl_xor(sum, st, 32);
    float rinv = 1.0f / sum;
    for (int l = g; l < L_SZ; l += 32) W_s[k][l] *= rinv;
    __syncthreads();

    float* dst = Wt_g + (long)(s - 1) * (K_SZ * L_SZ);
    for (int j = t; j < K_SZ * L_SZ; j += 256)
        dst[j] = W_s[j & 7][j >> 3];   // dst[l*8+k] = W[k][l]
}

// ---------------- route: block-per-batch, all-VALU broadcasts.
// grid 4096 x 256.  WRITE_OUT=1 (final iter): write squashed high, stop.
template<int WRITE_OUT>
__global__ __launch_bounds__(256, 8) void k_route4(const float* __restrict__ lc_g,
                                                   const int* __restrict__ seq_len,
                                                   const float* __restrict__ Wt_g,
                                                   const float* __restrict__ S_g,
                                                   const float* __restrict__ St_g,
                                                   float* __restrict__ partial,
                                                   float* __restrict__ out) {
    __shared__ float hp_part[4][K_SZ][DK];  // 8 KB
    __shared__ float hp_s[K_SZ][DK];        // 2 KB (reused as hx after high)
    __shared__ float hs_s[K_SZ][DK];        // 2 KB
    int t = threadIdx.x;
    int b = blockIdx.x;
    const float* __restrict__ lcb = lc_g + (long)b * (L_SZ * DK);
    int k = t >> 5, g = t & 31;
    int lam = t & 63;
    int w = __builtin_amdgcn_readfirstlane(t >> 6);   // wave-uniform

    int sl = seq_len[b];                              // uniform
    const float* __restrict__ wbase = Wt_g + (long)(sl - 1) * (K_SZ * L_SZ);

    // ---- Phase A: hp partials. Wave w owns rows l = w+4j (wave-uniform!):
    //      W row via scalar s_load_dwordx8; lc coalesced (lane = col). No DS.
    float acc[K_SZ] = {};
    {
        const float* lp = lcb + lam;
        #pragma unroll 2
        for (int j = 0; j < 50; ++j) {
            int l = w + 4 * j;                        // uniform chain -> SGPR
            float v = lp[l * DK];                     // 256B coalesced per wave
            const float* wr = wbase + l * K_SZ;       // uniform -> s_load
            acc[0] = fmaf(wr[0], v, acc[0]);
            acc[1] = fmaf(wr[1], v, acc[1]);
            acc[2] = fmaf(wr[2], v, acc[2]);
            acc[3] = fmaf(wr[3], v, acc[3]);
            acc[4] = fmaf(wr[4], v, acc[4]);
            acc[5] = fmaf(wr[5], v, acc[5]);
            acc[6] = fmaf(wr[6], v, acc[6]);
            acc[7] = fmaf(wr[7], v, acc[7]);
        }
        #pragma unroll
        for (int kk = 0; kk < K_SZ; ++kk) hp_part[w][kk][lam] = acc[kk];
    }
    __syncthreads();

    // ---- reduce 4 wave-partials -> hp_s (256 threads x float2)
    {
        int kk = t >> 5, ii = (t & 31) * 2;
        float2 r = make_float2(0.f, 0.f);
        #pragma unroll
        for (int ww = 0; ww < 4; ++ww) {
            float2 p = *(const float2*)&hp_part[ww][kk][ii];
            r.x += p.x; r.y += p.y;
        }
        *(float2*)&hp_s[kk][ii] = r;
    }
    __syncthreads();

    // ---- high[k][o] = sum_i hp[k][i]*S[i][o]; squash.  warp k, o=2g,2g+1
    float h0 = 0.f, h1 = 0.f;
    {
        const float* sp = S_g + 2 * g;
        #pragma unroll 8
        for (int i = 0; i < DK; ++i) {
            float pv = hp_s[k][i];                        // 2-addr broadcast
            float2 sv = *(const float2*)(sp + i * DK);    // L1-hot, coalesced
            h0 = fmaf(pv, sv.x, h0); h1 = fmaf(pv, sv.y, h1);
        }
        float nn = h0 * h0 + h1 * h1;
        #pragma unroll
        for (int st = 16; st; st >>= 1) nn += __shfl_xor(nn, st, 32);
        float sc = nn / ((1.0f + nn) * sqrtf(nn + 1e-9f));
        h0 *= sc; h1 *= sc;
    }
    if (WRITE_OUT) {
        float2* ob2 = (float2*)(out + (long)b * (K_SZ * DK) + k * DK);
        ob2[g] = make_float2(h0, h1);
        return;
    }
    *(float2*)&hp_s[k][2 * g] = make_float2(h0, h1);  // reuse as hx: same-warp RW

    // ---- hs[k][i] = sum_o high[k][o]*St[o][i]   warp k, i=2g,2g+1
    {
        float s0 = 0.f, s1 = 0.f;
        const float* stp = St_g + 2 * g;
        #pragma unroll 8
        for (int o = 0; o < DK; ++o) {
            float hv = hp_s[k][o];                        // same-warp broadcast
            float2 sv = *(const float2*)(stp + o * DK);   // L1-hot, coalesced
            s0 = fmaf(hv, sv.x, s0); s1 = fmaf(hv, sv.y, s1);
        }
        *(float2*)&hs_s[k][2 * g] = make_float2(s0, s1);
    }
    __syncthreads();

    // ---- Phase C: delta. Thread t owns row t (t<200); hs via readlane (VALU).
    float hsr[K_SZ];
    #pragma unroll
    for (int kk = 0; kk < K_SZ; ++kk) hsr[kk] = hs_s[kk][lam];  // stride-1, 8 reads
    if (t < L_SZ) {
        const float4* row4 = (const float4*)(lcb + (long)t * DK);  // L1/L2-hot
        float a[K_SZ] = {};
        #pragma unroll
        for (int i4 = 0; i4 < 16; ++i4) {
            float4 v = row4[i4];
            #pragma unroll
            for (int kk = 0; kk < K_SZ; ++kk) {
                a[kk] = fmaf(rl(hsr[kk], 4 * i4 + 0), v.x,
                        fmaf(rl(hsr[kk], 4 * i4 + 1), v.y,
                        fmaf(rl(hsr[kk], 4 * i4 + 2), v.z,
                        fmaf(rl(hsr[kk], 4 * i4 + 3), v.w, a[kk]))));
            }
        }
        float* pb = partial + (long)b * (K_SZ * L_SZ);
        #pragma unroll
        for (int kk = 0; kk < K_SZ; ++kk)
            pb[kk * L_SZ + t] = a[kk];       // coalesced over t
    }
}

// --------------------------- deterministic two-stage reduce of partials
__global__ __launch_bounds__(256) void k_reduceA(const float* __restrict__ partial,
                                                 float* __restrict__ partial2) {
    __shared__ float red[256];
    int x = blockIdx.x % 50;       // 32-output group
    int y = blockIdx.x / 50;       // 256-batch chunk
    int t = threadIdx.x;
    int i = x * 32 + (t & 31);
    int sub = t >> 5;
    float s = 0.f;
    for (int p = y * 256 + sub; p < (y + 1) * 256; p += 8)
        s += partial[(long)p * (K_SZ * L_SZ) + i];
    red[t] = s;
    __syncthreads();
    for (int step = 4; step >= 1; step >>= 1) {
        if (sub < step) red[t] += red[t + step * 32];
        __syncthreads();
    }
    if (sub == 0) partial2[y * (K_SZ * L_SZ) + i] = red[t];
}

__global__ __launch_bounds__(256) void k_reduceB(const float* __restrict__ partial2,
                                                 float* __restrict__ Bc) {
    int i = blockIdx.x * 256 + threadIdx.x;
    if (i < K_SZ * L_SZ) {
        float s = 0.f;
        #pragma unroll
        for (int y = 0; y < 16; ++y) s += partial2[y * (K_SZ * L_SZ) + i];
        Bc[i] += s;
    }
}

extern "C" void kernel_launch(void* const* d_in, const int* in_sizes, int n_in,
                              void* d_out, int out_size, void* d_ws, size_t ws_size,
                              hipStream_t stream) {
    const float* lc = (const float*)d_in[0];   // [4096,200,64]
    const int*   sl = (const int*)d_in[1];     // [4096,1]
    const float* Bm = (const float*)d_in[2];   // [1,8,200]
    const float* S  = (const float*)d_in[3];   // [64,64]
    float* out = (float*)d_out;                // [4096,8,64]
    float* ws  = (float*)d_ws;

    float* Bc      = ws;                       // 1,600
    float* St      = Bc + 1600;                // 4,096
    float* Wt      = St + 4096;                // 320,000  (s,l,k)
    float* partial = Wt + 200 * (K_SZ * L_SZ); // 6,553,600
    float* p2      = out;                      // scratch: overwritten by final pass

    k_init<<<23, 256, 0, stream>>>(Bm, S, Bc, St);

    k_soft     <<<200, 256, 0, stream>>>(Bc, Wt);
    k_route4<0><<<B_SZ, 256, 0, stream>>>(lc, sl, Wt, S, St, partial, out);
    k_reduceA  <<<800, 256, 0, stream>>>(partial, p2);
    k_reduceB  <<<7, 256, 0, stream>>>(p2, Bc);

    k_soft     <<<200, 256, 0, stream>>>(Bc, Wt);
    k_route4<0><<<B_SZ, 256, 0, stream>>>(lc, sl, Wt, S, St, partial, out);
    k_reduceA  <<<800, 256, 0, stream>>>(partial, p2);
    k_reduceB  <<<7, 256, 0, stream>>>(p2, Bc);

    k_soft     <<<200, 256, 0, stream>>>(Bc, Wt);
    k_route4<1><<<B_SZ, 256, 0, stream>>>(lc, sl, Wt, S, St, partial, out);
}

// Round 12
// 312.628 us; speedup vs baseline: 1.8670x; 1.0521x over previous
//
#include <hip/hip_runtime.h>
#include <math.h>

// CapsuleLayer dynamic routing, MI355X.
// B=4096, L=200, Din=Dout=64, K=8, 3 iterations.
//
// R11 -> R12: all block-per-batch variants pinned at ~1.3-1.5 TB/s effective
// stream rate (166us route) regardless of occupancy/DS/source; m13 float4
// copy does 6.3 TB/s. Lever under test: access granularity + MLP. Phase A
// rebuilt as m13-pattern linear float4 stream (1KB/wave-instr, 13 indep
// iters); thread owns 4 fixed cols x 8 k accumulators; W via 2 ds_read_b128
// from an XOR-swizzled [l][k] LDS table (conflict-free); fold via 2-level
// shfl butterfly. Everything else carried from R11.
//
// ws layout (floats):
//   Bc[1600] | St[4096] | Wt[200*1600 (s,k,l)] | partial[B*K*L]
// partial2 [16*K*L] lives in d_out (fully overwritten by the final pass).

#define B_SZ  4096
#define L_SZ  200
#define DK    64
#define K_SZ  8
#define KL    (K_SZ * L_SZ)

__device__ __forceinline__ float rl(float x, int i) {
    return __int_as_float(__builtin_amdgcn_readlane(__float_as_int(x), i));
}

// ---------------------------- init: copy Bc + transpose S into St
__global__ __launch_bounds__(256) void k_init(const float* __restrict__ Bm,
                                              const float* __restrict__ S,
                                              float* __restrict__ Bc,
                                              float* __restrict__ St) {
    int i = blockIdx.x * 256 + threadIdx.x;
    if (i < KL) Bc[i] = Bm[i];
    int j = i - KL;
    if (j >= 0 && j < DK * DK) {
        int o = j >> 6, ii = j & 63;
        St[j] = S[ii * DK + o];        // St[o][i] = S[i][o]
    }
}

// ---------------- softmax dedup: Wt[s-1][k][l] (k-major) for sl=s in 1..200
__global__ __launch_bounds__(256) void k_soft(const float* __restrict__ Bc,
                                              float* __restrict__ Wt_g) {
    __shared__ float W_s[K_SZ][L_SZ];
    int t = threadIdx.x;
    int s = blockIdx.x + 1;
    int k = t >> 5, g = t & 31;

    const float* bk = Bc + k * L_SZ;
    float m = -3.4e38f;
    for (int l = g; l < s; l += 32) m = fmaxf(m, bk[l]);
    #pragma unroll
    for (int st = 16; st; st >>= 1) m = fmaxf(m, __shfl_xor(m, st, 32));
    float sum = 0.f;
    for (int l = g; l < L_SZ; l += 32) {
        float e = (l < s) ? __expf(bk[l] - m) : 0.f;
        sum += e;
        W_s[k][l] = e;
    }
    #pragma unroll
    for (int st = 16; st; st >>= 1) sum += __shfl_xor(sum, st, 32);
    float rinv = 1.0f / sum;
    for (int l = g; l < L_SZ; l += 32) W_s[k][l] *= rinv;
    __syncthreads();

    float4* dst = (float4*)(Wt_g + (long)(s - 1) * KL);
    const float4* src = (const float4*)&W_s[0][0];
    for (int j = t; j < KL / 4; j += 256) dst[j] = src[j];   // linear (k,l)
}

// ---------------- route: m13-style float4 hp stream + R11 tail.
// grid 4096 x 256.  WRITE_OUT=1 (final iter): write squashed high, stop.
template<int WRITE_OUT>
__global__ __launch_bounds__(256, 6) void k_route5(const float* __restrict__ lc_g,
                                                   const int* __restrict__ seq_len,
                                                   const float* __restrict__ Wt_g,
                                                   const float* __restrict__ S_g,
                                                   const float* __restrict__ St_g,
                                                   float* __restrict__ partial,
                                                   float* __restrict__ out) {
    __shared__ float Wl[KL];                // 6.4 KB XOR-swizzled (l,k)
    __shared__ float hp_part[4][K_SZ][DK];  // 8 KB
    __shared__ float hp_s[K_SZ][DK];        // 2 KB (reused as hx)
    __shared__ float hs_s[K_SZ][DK];        // 2 KB
    int t = threadIdx.x;
    int b = blockIdx.x;
    const float* __restrict__ lcb = lc_g + (long)b * (L_SZ * DK);
    const float4* __restrict__ lc4 = (const float4*)lcb;
    int sl = seq_len[b];                    // uniform

    // stage W swizzled: W[k][l] -> Wl[(l*8+k) ^ ((l&3)<<2)]  (bijective;
    // read side uses the same XOR, so data maps identity, banks spread)
    {
        const float* __restrict__ src = Wt_g + (long)(sl - 1) * KL;
        for (int j = t; j < KL; j += 256) {
            int k = j / L_SZ;
            int l = j - k * L_SZ;
            Wl[(l * 8 + k) ^ ((l & 3) << 2)] = src[j];
        }
    }
    __syncthreads();

    int grp = t >> 4;                       // row-phase 0..15
    int w = t >> 6;                         // wave
    float4 a[8];                            // a[k] over this thread's 4 cols
    #pragma unroll
    for (int p = 0; p < 8; ++p) a[p] = make_float4(0.f, 0.f, 0.f, 0.f);

    // ---- Phase A: linear float4 stream. iter j: thread reads lc4[t+256j] =
    //      row (grp+16j), cols 4(t&15)..+3. 12 full iters + half-block tail.
    #pragma unroll 4
    for (int j = 0; j < 12; ++j) {
        float4 v = lc4[t + 256 * j];
        int r = grp + 16 * j;
        int c = (r & 3) << 2;
        float4 wa = *(const float4*)&Wl[(r * 8) ^ c];       // W[0..3][r]
        float4 wb = *(const float4*)&Wl[(r * 8 + 4) ^ c];   // W[4..7][r]
        float wk[8] = {wa.x, wa.y, wa.z, wa.w, wb.x, wb.y, wb.z, wb.w};
        #pragma unroll
        for (int p = 0; p < 8; ++p) {
            a[p].x = fmaf(wk[p], v.x, a[p].x);
            a[p].y = fmaf(wk[p], v.y, a[p].y);
            a[p].z = fmaf(wk[p], v.z, a[p].z);
            a[p].w = fmaf(wk[p], v.w, a[p].w);
        }
    }
    if (t < 128) {                          // rows 192..199 (predicate the LOAD)
        float4 v = lc4[t + 3072];
        int r = grp + 192;
        int c = (r & 3) << 2;
        float4 wa = *(const float4*)&Wl[(r * 8) ^ c];
        float4 wb = *(const float4*)&Wl[(r * 8 + 4) ^ c];
        float wk[8] = {wa.x, wa.y, wa.z, wa.w, wb.x, wb.y, wb.z, wb.w};
        #pragma unroll
        for (int p = 0; p < 8; ++p) {
            a[p].x = fmaf(wk[p], v.x, a[p].x);
            a[p].y = fmaf(wk[p], v.y, a[p].y);
            a[p].z = fmaf(wk[p], v.z, a[p].z);
            a[p].w = fmaf(wk[p], v.w, a[p].w);
        }
    }

    // ---- fold the 4 in-wave row-groups (butterfly over lanes ^16, ^32)
    #pragma unroll
    for (int p = 0; p < 8; ++p) {
        a[p].x += __shfl_xor(a[p].x, 16, 64);
        a[p].y += __shfl_xor(a[p].y, 16, 64);
        a[p].z += __shfl_xor(a[p].z, 16, 64);
        a[p].w += __shfl_xor(a[p].w, 16, 64);
        a[p].x += __shfl_xor(a[p].x, 32, 64);
        a[p].y += __shfl_xor(a[p].y, 32, 64);
        a[p].z += __shfl_xor(a[p].z, 32, 64);
        a[p].w += __shfl_xor(a[p].w, 32, 64);
    }
    if ((t & 63) < 16) {                    // all lanes hold the wave sum
        int c0 = (t & 15) * 4;
        #pragma unroll
        for (int p = 0; p < 8; ++p)
            *(float4*)&hp_part[w][p][c0] = a[p];   // 16 lanes x 16B: 2-way, free
    }
    __syncthreads();

    // ---- reduce 4 wave-partials -> hp_s
    {
        int kk = t >> 5, ii = (t & 31) * 2;
        float2 r2 = make_float2(0.f, 0.f);
        #pragma unroll
        for (int ww = 0; ww < 4; ++ww) {
            float2 p = *(const float2*)&hp_part[ww][kk][ii];
            r2.x += p.x; r2.y += p.y;
        }
        *(float2*)&hp_s[kk][ii] = r2;
    }
    __syncthreads();

    // ---- high[k][o] = sum_i hp[k][i]*S[i][o]; squash.  warp k, o=2g,2g+1
    int k = t >> 5, g = t & 31;
    int lam = t & 63;
    float h0 = 0.f, h1 = 0.f;
    {
        const float* sp = S_g + 2 * g;
        #pragma unroll 8
        for (int i = 0; i < DK; ++i) {
            float pv = hp_s[k][i];                        // 2-addr broadcast
            float2 sv = *(const float2*)(sp + i * DK);    // L1-hot, coalesced
            h0 = fmaf(pv, sv.x, h0); h1 = fmaf(pv, sv.y, h1);
        }
        float nn = h0 * h0 + h1 * h1;
        #pragma unroll
        for (int st = 16; st; st >>= 1) nn += __shfl_xor(nn, st, 32);
        float sc = nn / ((1.0f + nn) * sqrtf(nn + 1e-9f));
        h0 *= sc; h1 *= sc;
    }
    if (WRITE_OUT) {
        float2* ob2 = (float2*)(out + (long)b * (K_SZ * DK) + k * DK);
        ob2[g] = make_float2(h0, h1);
        return;
    }
    *(float2*)&hp_s[k][2 * g] = make_float2(h0, h1);  // reuse as hx: same-warp RW

    // ---- hs[k][i] = sum_o high[k][o]*St[o][i]   warp k, i=2g,2g+1
    {
        float s0 = 0.f, s1 = 0.f;
        const float* stp = St_g + 2 * g;
        #pragma unroll 8
        for (int o = 0; o < DK; ++o) {
            float hv = hp_s[k][o];                        // same-warp broadcast
            float2 sv = *(const float2*)(stp + o * DK);   // L1-hot, coalesced
            s0 = fmaf(hv, sv.x, s0); s1 = fmaf(hv, sv.y, s1);
        }
        *(float2*)&hs_s[k][2 * g] = make_float2(s0, s1);
    }
    __syncthreads();

    // ---- delta: thread t owns row t (t<200); hs broadcast via readlane.
    float hsr[K_SZ];
    #pragma unroll
    for (int kk = 0; kk < K_SZ; ++kk) hsr[kk] = hs_s[kk][lam];  // stride-1
    if (t < L_SZ) {
        const float4* row4 = (const float4*)(lcb + (long)t * DK);  // just streamed
        float aa[K_SZ] = {};
        #pragma unroll
        for (int i4 = 0; i4 < 16; ++i4) {
            float4 v = row4[i4];
            #pragma unroll
            for (int kk = 0; kk < K_SZ; ++kk) {
                aa[kk] = fmaf(rl(hsr[kk], 4 * i4 + 0), v.x,
                         fmaf(rl(hsr[kk], 4 * i4 + 1), v.y,
                         fmaf(rl(hsr[kk], 4 * i4 + 2), v.z,
                         fmaf(rl(hsr[kk], 4 * i4 + 3), v.w, aa[kk]))));
            }
        }
        float* pb = partial + (long)b * KL;
        #pragma unroll
        for (int kk = 0; kk < K_SZ; ++kk)
            pb[kk * L_SZ + t] = aa[kk];      // coalesced over t
    }
}

// --------------------------- deterministic two-stage reduce of partials
__global__ __launch_bounds__(256) void k_reduceA(const float* __restrict__ partial,
                                                 float* __restrict__ partial2) {
    __shared__ float red[256];
    int x = blockIdx.x % 50;
    int y = blockIdx.x / 50;
    int t = threadIdx.x;
    int i = x * 32 + (t & 31);
    int sub = t >> 5;
    float s = 0.f;
    for (int p = y * 256 + sub; p < (y + 1) * 256; p += 8)
        s += partial[(long)p * KL + i];
    red[t] = s;
    __syncthreads();
    for (int step = 4; step >= 1; step >>= 1) {
        if (sub < step) red[t] += red[t + step * 32];
        __syncthreads();
    }
    if (sub == 0) partial2[y * KL + i] = red[t];
}

__global__ __launch_bounds__(256) void k_reduceB(const float* __restrict__ partial2,
                                                 float* __restrict__ Bc) {
    int i = blockIdx.x * 256 + threadIdx.x;
    if (i < KL) {
        float s = 0.f;
        #pragma unroll
        for (int y = 0; y < 16; ++y) s += partial2[y * KL + i];
        Bc[i] += s;
    }
}

extern "C" void kernel_launch(void* const* d_in, const int* in_sizes, int n_in,
                              void* d_out, int out_size, void* d_ws, size_t ws_size,
                              hipStream_t stream) {
    const float* lc = (const float*)d_in[0];   // [4096,200,64]
    const int*   sl = (const int*)d_in[1];     // [4096,1]
    const float* Bm = (const float*)d_in[2];   // [1,8,200]
    const float* S  = (const float*)d_in[3];   // [64,64]
    float* out = (float*)d_out;                // [4096,8,64]
    float* ws  = (float*)d_ws;

    float* Bc      = ws;                       // 1,600
    float* St      = Bc + 1600;                // 4,096
    float* Wt      = St + 4096;                // 320,000  (s,k,l)
    float* partial = Wt + 200 * KL;            // 6,553,600
    float* p2      = out;                      // scratch: overwritten by final pass

    k_init<<<23, 256, 0, stream>>>(Bm, S, Bc, St);

    k_soft     <<<200, 256, 0, stream>>>(Bc, Wt);
    k_route5<0><<<B_SZ, 256, 0, stream>>>(lc, sl, Wt, S, St, partial, out);
    k_reduceA  <<<800, 256, 0, stream>>>(partial, p2);
    k_reduceB  <<<7, 256, 0, stream>>>(p2, Bc);

    k_soft     <<<200, 256, 0, stream>>>(Bc, Wt);
    k_route5<0><<<B_SZ, 256, 0, stream>>>(lc, sl, Wt, S, St, partial, out);
    k_reduceA  <<<800, 256, 0, stream>>>(partial, p2);
    k_reduceB  <<<7, 256, 0, stream>>>(p2, Bc);

    k_soft     <<<200, 256, 0, stream>>>(Bc, Wt);
    k_route5<1><<<B_SZ, 256, 0, stream>>>(lc, sl, Wt, S, St, partial, out);
}

// Round 13
// 301.162 us; speedup vs baseline: 1.9380x; 1.0381x over previous
//
#include <hip/hip_runtime.h>
#include <math.h>

// CapsuleLayer dynamic routing, MI355X.
// B=4096, L=200, Din=Dout=64, K=8, 3 iterations.
//
// R12 -> R13: real route time is ~85-90us (rocprof per-dispatch numbers carry
// a large constant inflation; 3x158 > 313 total proved it). Remaining fat is
// orchestration: 14 launches -> 8 by fusing reduceB+softmax+W-table into one
// k_table kernel (grid 200, block per seq-len value; redundant 102KB L2 reads
// beat two extra launches). W staging de-swizzled: Wt stored (l,k) so route
// stages with a linear float4 copy; phase A's b128 pairs naturally cover all
// 32 banks (R12's XOR only broke the staging writes -> 1.37M conflicts).
//
// ws layout (floats): St[4096] | Wt[200*1600 (s,l,k)] | Bc[1600] | partial[B*K*L]
// p2[16*1600] lives in d_out (overwritten by the final route pass).

#define B_SZ  4096
#define L_SZ  200
#define DK    64
#define K_SZ  8
#define KL    1600

__device__ __forceinline__ float rl(float x, int i) {
    return __int_as_float(__builtin_amdgcn_readlane(__float_as_int(x), i));
}

// ---------------- table kernel: one block per seq-len s = blockIdx+1.
// INIT=1 (k_pre): Bv = Bm; block 200 does the St transpose instead.
// INIT=0 (bupdate): Bv = BcIn + sum_y p2[y]; block 0 writes BcOut if WRITE_BC.
// Writes Wt[s-1][l*8+k] (l-major, coalesced).
template<int INIT, int WRITE_BC>
__global__ __launch_bounds__(256) void k_table(const float* __restrict__ Bm,
                                               const float* __restrict__ S,
                                               const float* __restrict__ p2,
                                               const float* __restrict__ BcIn,
                                               float* __restrict__ BcOut,
                                               float* __restrict__ St,
                                               float* __restrict__ Wt) {
    int t = threadIdx.x;
    int blk = blockIdx.x;
    if (INIT && blk == 200) {          // St[o][i] = S[i][o]
        for (int j = t; j < DK * DK; j += 256) {
            int o = j >> 6, ii = j & 63;
            St[j] = S[ii * DK + o];
        }
        return;
    }
    __shared__ float Bv[KL];           // k-major: Bv[k*200+l]
    __shared__ float mArr[K_SZ], rArr[K_SZ];
    int s = blk + 1;                   // seq-len this block covers

    for (int j = t; j < KL; j += 256) {
        float bn;
        if (INIT) {
            bn = Bm[j];
        } else {
            float acc = 0.f;
            #pragma unroll
            for (int y = 0; y < 16; ++y) acc += p2[y * KL + j];   // L2-hot
            bn = BcIn[j] + acc;
            if (WRITE_BC && blk == 0) BcOut[j] = bn;  // other blocks read BcIn!=BcOut
        }
        Bv[j] = bn;
    }
    __syncthreads();

    // warp k: masked softmax stats over l < s
    int k = t >> 5, g = t & 31;
    const float* bk = &Bv[k * L_SZ];
    float m = -3.4e38f;
    for (int l = g; l < s; l += 32) m = fmaxf(m, bk[l]);
    #pragma unroll
    for (int st = 16; st; st >>= 1) m = fmaxf(m, __shfl_xor(m, st, 32));
    float sum = 0.f;
    for (int l = g; l < s; l += 32) sum += __expf(bk[l] - m);
    #pragma unroll
    for (int st = 16; st; st >>= 1) sum += __shfl_xor(sum, st, 32);
    if (g == 0) { mArr[k] = m; rArr[k] = 1.0f / sum; }
    __syncthreads();

    // write the (l,k) table slice, fully coalesced
    float* dst = Wt + (long)(s - 1) * KL;
    for (int j = t; j < KL; j += 256) {
        int l = j >> 3, kk = j & 7;
        dst[j] = (l < s) ? __expf(Bv[kk * L_SZ + l] - mArr[kk]) * rArr[kk] : 0.f;
    }
}

// ---------------- route: linear-W-stage + float4 lc stream + R11 tail.
// grid 4096 x 256.  WRITE_OUT=1 (final iter): write squashed high, stop.
template<int WRITE_OUT>
__global__ __launch_bounds__(256, 6) void k_route6(const float* __restrict__ lc_g,
                                                   const int* __restrict__ seq_len,
                                                   const float* __restrict__ Wt_g,
                                                   const float* __restrict__ S_g,
                                                   const float* __restrict__ St_g,
                                                   float* __restrict__ partial,
                                                   float* __restrict__ out) {
    __shared__ float Wl[KL];                // 6.4 KB, layout l*8+k (NO swizzle)
    __shared__ float hp_part[4][K_SZ][DK];  // 8 KB
    __shared__ float hp_s[K_SZ][DK];        // 2 KB (reused as hx)
    __shared__ float hs_s[K_SZ][DK];        // 2 KB
    int t = threadIdx.x;
    int b = blockIdx.x;
    const float* __restrict__ lcb = lc_g + (long)b * (L_SZ * DK);
    const float4* __restrict__ lc4 = (const float4*)lcb;
    int sl = seq_len[b];                    // uniform

    // stage W: pure linear float4 copy (coalesced global, conflict-free LDS)
    {
        const float4* __restrict__ src =
            (const float4*)(Wt_g + (long)(sl - 1) * KL);
        float4* dst = (float4*)Wl;
        for (int j = t; j < KL / 4; j += 256) dst[j] = src[j];
    }
    __syncthreads();

    int grp = t >> 4;                       // row-phase 0..15
    int w = t >> 6;                         // wave
    float4 a[8];                            // a[k] over this thread's 4 cols
    #pragma unroll
    for (int p = 0; p < 8; ++p) a[p] = make_float4(0.f, 0.f, 0.f, 0.f);

    // Phase A: linear float4 stream; iter j: row (grp+16j), cols 4(t&15)..+3.
    // W row r: Wl[r*8..r*8+7] -- 4 rows/wave x 8 words = all 32 banks once.
    #pragma unroll 4
    for (int j = 0; j < 12; ++j) {
        float4 v = lc4[t + 256 * j];
        int r = grp + 16 * j;
        float4 wa = *(const float4*)&Wl[r * 8];       // W[r][k=0..3]
        float4 wb = *(const float4*)&Wl[r * 8 + 4];   // W[r][k=4..7]
        float wk[8] = {wa.x, wa.y, wa.z, wa.w, wb.x, wb.y, wb.z, wb.w};
        #pragma unroll
        for (int p = 0; p < 8; ++p) {
            a[p].x = fmaf(wk[p], v.x, a[p].x);
            a[p].y = fmaf(wk[p], v.y, a[p].y);
            a[p].z = fmaf(wk[p], v.z, a[p].z);
            a[p].w = fmaf(wk[p], v.w, a[p].w);
        }
    }
    if (t < 128) {                          // rows 192..199
        float4 v = lc4[t + 3072];
        int r = grp + 192;
        float4 wa = *(const float4*)&Wl[r * 8];
        float4 wb = *(const float4*)&Wl[r * 8 + 4];
        float wk[8] = {wa.x, wa.y, wa.z, wa.w, wb.x, wb.y, wb.z, wb.w};
        #pragma unroll
        for (int p = 0; p < 8; ++p) {
            a[p].x = fmaf(wk[p], v.x, a[p].x);
            a[p].y = fmaf(wk[p], v.y, a[p].y);
            a[p].z = fmaf(wk[p], v.z, a[p].z);
            a[p].w = fmaf(wk[p], v.w, a[p].w);
        }
    }

    // fold 4 in-wave row-groups (butterfly ^16, ^32)
    #pragma unroll
    for (int p = 0; p < 8; ++p) {
        a[p].x += __shfl_xor(a[p].x, 16, 64);
        a[p].y += __shfl_xor(a[p].y, 16, 64);
        a[p].z += __shfl_xor(a[p].z, 16, 64);
        a[p].w += __shfl_xor(a[p].w, 16, 64);
        a[p].x += __shfl_xor(a[p].x, 32, 64);
        a[p].y += __shfl_xor(a[p].y, 32, 64);
        a[p].z += __shfl_xor(a[p].z, 32, 64);
        a[p].w += __shfl_xor(a[p].w, 32, 64);
    }
    if ((t & 63) < 16) {
        int c0 = (t & 15) * 4;
        #pragma unroll
        for (int p = 0; p < 8; ++p)
            *(float4*)&hp_part[w][p][c0] = a[p];
    }
    __syncthreads();

    // reduce 4 wave-partials -> hp_s
    {
        int kk = t >> 5, ii = (t & 31) * 2;
        float2 r2 = make_float2(0.f, 0.f);
        #pragma unroll
        for (int ww = 0; ww < 4; ++ww) {
            float2 p = *(const float2*)&hp_part[ww][kk][ii];
            r2.x += p.x; r2.y += p.y;
        }
        *(float2*)&hp_s[kk][ii] = r2;
    }
    __syncthreads();

    // high[k][o] = sum_i hp[k][i]*S[i][o]; squash.  warp k, o=2g,2g+1
    int k = t >> 5, g = t & 31;
    int lam = t & 63;
    float h0 = 0.f, h1 = 0.f;
    {
        const float* sp = S_g + 2 * g;
        #pragma unroll 8
        for (int i = 0; i < DK; ++i) {
            float pv = hp_s[k][i];                        // broadcast
            float2 sv = *(const float2*)(sp + i * DK);    // L1-hot, coalesced
            h0 = fmaf(pv, sv.x, h0); h1 = fmaf(pv, sv.y, h1);
        }
        float nn = h0 * h0 + h1 * h1;
        #pragma unroll
        for (int st = 16; st; st >>= 1) nn += __shfl_xor(nn, st, 32);
        float sc = nn / ((1.0f + nn) * sqrtf(nn + 1e-9f));
        h0 *= sc; h1 *= sc;
    }
    if (WRITE_OUT) {
        float2* ob2 = (float2*)(out + (long)b * (K_SZ * DK) + k * DK);
        ob2[g] = make_float2(h0, h1);
        return;
    }
    *(float2*)&hp_s[k][2 * g] = make_float2(h0, h1);  // reuse as hx: same-warp RW

    // hs[k][i] = sum_o high[k][o]*St[o][i]   warp k, i=2g,2g+1
    {
        float s0 = 0.f, s1 = 0.f;
        const float* stp = St_g + 2 * g;
        #pragma unroll 8
        for (int o = 0; o < DK; ++o) {
            float hv = hp_s[k][o];                        // same-warp broadcast
            float2 sv = *(const float2*)(stp + o * DK);   // L1-hot, coalesced
            s0 = fmaf(hv, sv.x, s0); s1 = fmaf(hv, sv.y, s1);
        }
        *(float2*)&hs_s[k][2 * g] = make_float2(s0, s1);
    }
    __syncthreads();

    // delta: thread t owns row t (t<200); hs broadcast via readlane (VALU).
    float hsr[K_SZ];
    #pragma unroll
    for (int kk = 0; kk < K_SZ; ++kk) hsr[kk] = hs_s[kk][lam];  // 2-way, free
    if (t < L_SZ) {
        const float4* row4 = (const float4*)(lcb + (long)t * DK);  // just streamed
        float aa[K_SZ] = {};
        #pragma unroll
        for (int i4 = 0; i4 < 16; ++i4) {
            float4 v = row4[i4];
            #pragma unroll
            for (int kk = 0; kk < K_SZ; ++kk) {
                aa[kk] = fmaf(rl(hsr[kk], 4 * i4 + 0), v.x,
                         fmaf(rl(hsr[kk], 4 * i4 + 1), v.y,
                         fmaf(rl(hsr[kk], 4 * i4 + 2), v.z,
                         fmaf(rl(hsr[kk], 4 * i4 + 3), v.w, aa[kk]))));
            }
        }
        float* pb = partial + (long)b * KL;
        #pragma unroll
        for (int kk = 0; kk < K_SZ; ++kk)
            pb[kk * L_SZ + t] = aa[kk];      // coalesced over t
    }
}

// --------------------------- stage-A reduce of partials (unchanged)
__global__ __launch_bounds__(256) void k_reduceA(const float* __restrict__ partial,
                                                 float* __restrict__ partial2) {
    __shared__ float red[256];
    int x = blockIdx.x % 50;
    int y = blockIdx.x / 50;
    int t = threadIdx.x;
    int i = x * 32 + (t & 31);
    int sub = t >> 5;
    float s = 0.f;
    for (int p = y * 256 + sub; p < (y + 1) * 256; p += 8)
        s += partial[(long)p * KL + i];
    red[t] = s;
    __syncthreads();
    for (int step = 4; step >= 1; step >>= 1) {
        if (sub < step) red[t] += red[t + step * 32];
        __syncthreads();
    }
    if (sub == 0) partial2[y * KL + i] = red[t];
}

extern "C" void kernel_launch(void* const* d_in, const int* in_sizes, int n_in,
                              void* d_out, int out_size, void* d_ws, size_t ws_size,
                              hipStream_t stream) {
    const float* lc = (const float*)d_in[0];   // [4096,200,64]
    const int*   sl = (const int*)d_in[1];     // [4096,1]
    const float* Bm = (const float*)d_in[2];   // [1,8,200]
    const float* S  = (const float*)d_in[3];   // [64,64]
    float* out = (float*)d_out;                // [4096,8,64]
    float* ws  = (float*)d_ws;

    float* St      = ws;                       // 4,096
    float* Wt      = St + 4096;                // 320,000  (s,l,k)
    float* Bc      = Wt + 200 * KL;            // 1,600
    float* partial = Bc + KL;                  // 6,553,600
    float* p2      = out;                      // 25,600: overwritten by final pass

    // 8 launches total.
    k_table<1,0><<<201, 256, 0, stream>>>(Bm, S, p2, Bm, Bc, St, Wt);

    k_route6<0><<<B_SZ, 256, 0, stream>>>(lc, sl, Wt, S, St, partial, out);
    k_reduceA  <<<800, 256, 0, stream>>>(partial, p2);
    k_table<0,1><<<200, 256, 0, stream>>>(Bm, S, p2, /*BcIn=*/Bm, /*BcOut=*/Bc, St, Wt);

    k_route6<0><<<B_SZ, 256, 0, stream>>>(lc, sl, Wt, S, St, partial, out);
    k_reduceA  <<<800, 256, 0, stream>>>(partial, p2);
    k_table<0,0><<<200, 256, 0, stream>>>(Bm, S, p2, /*BcIn=*/Bc, /*BcOut=*/Bc, St, Wt);

    k_route6<1><<<B_SZ, 256, 0, stream>>>(lc, sl, Wt, S, St, partial, out);
}

// Round 14
// 279.026 us; speedup vs baseline: 2.0918x; 1.0793x over previous
//
#include <hip/hip_runtime.h>
#include <math.h>

// CapsuleLayer dynamic routing, MI355X.
// B=4096, L=200, Din=Dout=64, K=8, 3 iterations.
//
// R13 -> R14: route ~88us real = phaseA ~48 + delta ~40. Delta's row-owned
// loads are maximally uncoalesced (64 lines/wave-instr, 16B used of each;
// L1 thrash) and its hs broadcast is a 512-readlane storm. Fix: RETAIN the
// 13 phase-A float4 in registers (thread t holds rows grp+16j, cols 4(t&15)),
// compute per-row dot4 partials vs hs4 (staged once, free), scatter to a
// stride-18 LDS buffer (<=2-way), fold 16 lanes -> partial. Deletes the 2nd
// lc pass + readlanes; adds ~200 cheap DS ops + 26 barriers. VGPR ~110 ->
// __launch_bounds__(256,4); LDS unchanged 18.7KB via Wl/hp_part overlay.
//
// ws layout (floats): St[4096] | Wt[200*1600 (s,l,k)] | Bc[1600] | partial[B*K*L]
// p2[16*1600] lives in d_out (overwritten by the final route pass).

#define B_SZ  4096
#define L_SZ  200
#define DK    64
#define K_SZ  8
#define KL    1600

// ---------------- table kernel: one block per seq-len s = blockIdx+1.
// INIT=1: Bv = Bm; block 200 does the St transpose. INIT=0: Bv = BcIn+sum p2.
template<int INIT, int WRITE_BC>
__global__ __launch_bounds__(256) void k_table(const float* __restrict__ Bm,
                                               const float* __restrict__ S,
                                               const float* __restrict__ p2,
                                               const float* __restrict__ BcIn,
                                               float* __restrict__ BcOut,
                                               float* __restrict__ St,
                                               float* __restrict__ Wt) {
    int t = threadIdx.x;
    int blk = blockIdx.x;
    if (INIT && blk == 200) {          // St[o][i] = S[i][o]
        for (int j = t; j < DK * DK; j += 256) {
            int o = j >> 6, ii = j & 63;
            St[j] = S[ii * DK + o];
        }
        return;
    }
    __shared__ float Bv[KL];           // k-major: Bv[k*200+l]
    __shared__ float mArr[K_SZ], rArr[K_SZ];
    int s = blk + 1;

    for (int j = t; j < KL; j += 256) {
        float bn;
        if (INIT) {
            bn = Bm[j];
        } else {
            float acc = 0.f;
            #pragma unroll
            for (int y = 0; y < 16; ++y) acc += p2[y * KL + j];   // L2-hot
            bn = BcIn[j] + acc;
            if (WRITE_BC && blk == 0) BcOut[j] = bn;
        }
        Bv[j] = bn;
    }
    __syncthreads();

    int k = t >> 5, g = t & 31;
    const float* bk = &Bv[k * L_SZ];
    float m = -3.4e38f;
    for (int l = g; l < s; l += 32) m = fmaxf(m, bk[l]);
    #pragma unroll
    for (int st = 16; st; st >>= 1) m = fmaxf(m, __shfl_xor(m, st, 32));
    float sum = 0.f;
    for (int l = g; l < s; l += 32) sum += __expf(bk[l] - m);
    #pragma unroll
    for (int st = 16; st; st >>= 1) sum += __shfl_xor(sum, st, 32);
    if (g == 0) { mArr[k] = m; rArr[k] = 1.0f / sum; }
    __syncthreads();

    float* dst = Wt + (long)(s - 1) * KL;
    for (int j = t; j < KL; j += 256) {
        int l = j >> 3, kk = j & 7;
        dst[j] = (l < s) ? __expf(Bv[kk * L_SZ + l] - mArr[kk]) * rArr[kk] : 0.f;
    }
}

// ---------------- route: register-resident lc; delta from registers.
// grid 4096 x 256.  WRITE_OUT=1 (final iter): write squashed high, stop.
template<int WRITE_OUT>
__global__ __launch_bounds__(256, 4) void k_route7(const float* __restrict__ lc_g,
                                                   const int* __restrict__ seq_len,
                                                   const float* __restrict__ Wt_g,
                                                   const float* __restrict__ S_g,
                                                   const float* __restrict__ St_g,
                                                   float* __restrict__ partial,
                                                   float* __restrict__ out) {
    __shared__ float smem[3648];            // [0..1599]=Wl, [1600..3647]=hp_part;
                                            // delta scatter reuses [0..2303] (stride 18)
    __shared__ float hp_s[K_SZ][DK];        // 2 KB (reused as hx)
    __shared__ float hs_s[K_SZ][DK];        // 2 KB
    float* Wl = smem;
    float* hp_part = smem + 1600;           // [4][8][64]

    int t = threadIdx.x;
    int b = blockIdx.x;
    const float4* __restrict__ lc4 =
        (const float4*)(lc_g + (long)b * (L_SZ * DK));
    int sl = seq_len[b];                    // uniform

    // stage W: linear float4 copy (coalesced global, conflict-free LDS)
    {
        const float4* __restrict__ src =
            (const float4*)(Wt_g + (long)(sl - 1) * KL);
        float4* dst = (float4*)Wl;
        for (int j = t; j < KL / 4; j += 256) dst[j] = src[j];
    }
    __syncthreads();

    int grp = t >> 4;                       // row-phase 0..15
    int w = t >> 6;                         // wave

    // ---- load ALL of this thread's lc slice up front (13 loads in flight)
    float4 v[13];
    #pragma unroll
    for (int j = 0; j < 12; ++j) v[j] = lc4[t + 256 * j];
    if (t < 128) v[12] = lc4[t + 3072];
    else         v[12] = make_float4(0.f, 0.f, 0.f, 0.f);

    // ---- Phase A: hp partials from registers
    float4 a[8];
    #pragma unroll
    for (int p = 0; p < 8; ++p) a[p] = make_float4(0.f, 0.f, 0.f, 0.f);
    #pragma unroll
    for (int j = 0; j < 13; ++j) {
        int r = (j == 12) ? ((t < 128) ? 192 + grp : 199) : grp + 16 * j;
        float4 wa = *(const float4*)&Wl[r * 8];       // W[r][k=0..3]
        float4 wb = *(const float4*)&Wl[r * 8 + 4];   // W[r][k=4..7]
        float wk[8] = {wa.x, wa.y, wa.z, wa.w, wb.x, wb.y, wb.z, wb.w};
        #pragma unroll
        for (int p = 0; p < 8; ++p) {
            a[p].x = fmaf(wk[p], v[j].x, a[p].x);
            a[p].y = fmaf(wk[p], v[j].y, a[p].y);
            a[p].z = fmaf(wk[p], v[j].z, a[p].z);
            a[p].w = fmaf(wk[p], v[j].w, a[p].w);
        }
    }

    // fold 4 in-wave row-groups (butterfly ^16, ^32)
    #pragma unroll
    for (int p = 0; p < 8; ++p) {
        a[p].x += __shfl_xor(a[p].x, 16, 64);
        a[p].y += __shfl_xor(a[p].y, 16, 64);
        a[p].z += __shfl_xor(a[p].z, 16, 64);
        a[p].w += __shfl_xor(a[p].w, 16, 64);
        a[p].x += __shfl_xor(a[p].x, 32, 64);
        a[p].y += __shfl_xor(a[p].y, 32, 64);
        a[p].z += __shfl_xor(a[p].z, 32, 64);
        a[p].w += __shfl_xor(a[p].w, 32, 64);
    }
    if ((t & 63) < 16) {
        int c0 = (t & 15) * 4;
        #pragma unroll
        for (int p = 0; p < 8; ++p)
            *(float4*)&hp_part[w * 512 + p * 64 + c0] = a[p];
    }
    __syncthreads();

    // reduce 4 wave-partials -> hp_s
    {
        int kk = t >> 5, ii = (t & 31) * 2;
        float2 r2 = make_float2(0.f, 0.f);
        #pragma unroll
        for (int ww = 0; ww < 4; ++ww) {
            float2 p = *(const float2*)&hp_part[ww * 512 + kk * 64 + ii];
            r2.x += p.x; r2.y += p.y;
        }
        *(float2*)&hp_s[kk][ii] = r2;
    }
    __syncthreads();

    // high[k][o] = sum_i hp[k][i]*S[i][o]; squash.  warp k, o=2g,2g+1
    int k = t >> 5, g = t & 31;
    float h0 = 0.f, h1 = 0.f;
    {
        const float* sp = S_g + 2 * g;
        #pragma unroll 8
        for (int i = 0; i < DK; ++i) {
            float pv = hp_s[k][i];                        // broadcast
            float2 sv = *(const float2*)(sp + i * DK);    // L1-hot, coalesced
            h0 = fmaf(pv, sv.x, h0); h1 = fmaf(pv, sv.y, h1);
        }
        float nn = h0 * h0 + h1 * h1;
        #pragma unroll
        for (int st = 16; st; st >>= 1) nn += __shfl_xor(nn, st, 32);
        float sc = nn / ((1.0f + nn) * sqrtf(nn + 1e-9f));
        h0 *= sc; h1 *= sc;
    }
    if (WRITE_OUT) {
        float2* ob2 = (float2*)(out + (long)b * (K_SZ * DK) + k * DK);
        ob2[g] = make_float2(h0, h1);
        return;                              // uniform early exit
    }
    *(float2*)&hp_s[k][2 * g] = make_float2(h0, h1);  // reuse as hx: same-warp RW

    // hs[k][i] = sum_o high[k][o]*St[o][i]   warp k, i=2g,2g+1
    {
        float s0 = 0.f, s1 = 0.f;
        const float* stp = St_g + 2 * g;
        #pragma unroll 8
        for (int o = 0; o < DK; ++o) {
            float hv = hp_s[k][o];                        // same-warp broadcast
            float2 sv = *(const float2*)(stp + o * DK);   // L1-hot, coalesced
            s0 = fmaf(hv, sv.x, s0); s1 = fmaf(hv, sv.y, s1);
        }
        *(float2*)&hs_s[k][2 * g] = make_float2(s0, s1);
    }
    __syncthreads();

    // ---- delta from registers: thread t holds rows grp+16j, cols c0..c0+3.
    float4 hs4[8];
    int c0 = 4 * (t & 15);
    #pragma unroll
    for (int kk = 0; kk < 8; ++kk)
        hs4[kk] = *(const float4*)&hs_s[kk][c0];   // 2-way broadcast, free

    float* pb = partial + (long)b * KL;
    int lane16 = t & 15;
    #pragma unroll
    for (int j = 0; j < 13; ++j) {
        if (j < 12 || t < 128) {                   // valid rows only
            #pragma unroll
            for (int kk = 0; kk < 8; ++kk) {
                float4 h = hs4[kk];
                float p = v[j].x * h.x + v[j].y * h.y + v[j].z * h.z + v[j].w * h.w;
                smem[(grp * 8 + kk) * 18 + lane16] = p;   // <=2-way banks
            }
        }
        __syncthreads();
        int nOut = (j < 12) ? 128 : 64;
        if (t < nOut) {
            int s = t >> 3, kk = t & 7;            // s = row slot
            int r = 16 * j + s;
            const float2* q = (const float2*)&smem[(s * 8 + kk) * 18];
            float2 q0 = q[0], q1 = q[1], q2 = q[2], q3 = q[3];
            float2 q4 = q[4], q5 = q[5], q6 = q[6], q7 = q[7];
            float sum = ((q0.x + q0.y) + (q1.x + q1.y))
                      + ((q2.x + q2.y) + (q3.x + q3.y))
                      + ((q4.x + q4.y) + (q5.x + q5.y))
                      + ((q6.x + q6.y) + (q7.x + q7.y));
            pb[kk * L_SZ + r] = sum;
        }
        __syncthreads();
    }
}

// --------------------------- stage-A reduce of partials (unchanged)
__global__ __launch_bounds__(256) void k_reduceA(const float* __restrict__ partial,
                                                 float* __restrict__ partial2) {
    __shared__ float red[256];
    int x = blockIdx.x % 50;
    int y = blockIdx.x / 50;
    int t = threadIdx.x;
    int i = x * 32 + (t & 31);
    int sub = t >> 5;
    float s = 0.f;
    for (int p = y * 256 + sub; p < (y + 1) * 256; p += 8)
        s += partial[(long)p * KL + i];
    red[t] = s;
    __syncthreads();
    for (int step = 4; step >= 1; step >>= 1) {
        if (sub < step) red[t] += red[t + step * 32];
        __syncthreads();
    }
    if (sub == 0) partial2[y * KL + i] = red[t];
}

extern "C" void kernel_launch(void* const* d_in, const int* in_sizes, int n_in,
                              void* d_out, int out_size, void* d_ws, size_t ws_size,
                              hipStream_t stream) {
    const float* lc = (const float*)d_in[0];   // [4096,200,64]
    const int*   sl = (const int*)d_in[1];     // [4096,1]
    const float* Bm = (const float*)d_in[2];   // [1,8,200]
    const float* S  = (const float*)d_in[3];   // [64,64]
    float* out = (float*)d_out;                // [4096,8,64]
    float* ws  = (float*)d_ws;

    float* St      = ws;                       // 4,096
    float* Wt      = St + 4096;                // 320,000  (s,l,k)
    float* Bc      = Wt + 200 * KL;            // 1,600
    float* partial = Bc + KL;                  // 6,553,600
    float* p2      = out;                      // 25,600: overwritten by final pass

    // 8 launches total.
    k_table<1,0><<<201, 256, 0, stream>>>(Bm, S, p2, Bm, Bc, St, Wt);

    k_route7<0><<<B_SZ, 256, 0, stream>>>(lc, sl, Wt, S, St, partial, out);
    k_reduceA  <<<800, 256, 0, stream>>>(partial, p2);
    k_table<0,1><<<200, 256, 0, stream>>>(Bm, S, p2, /*BcIn=*/Bm, /*BcOut=*/Bc, St, Wt);

    k_route7<0><<<B_SZ, 256, 0, stream>>>(lc, sl, Wt, S, St, partial, out);
    k_reduceA  <<<800, 256, 0, stream>>>(partial, p2);
    k_table<0,0><<<200, 256, 0, stream>>>(Bm, S, p2, /*BcIn=*/Bc, /*BcOut=*/Bc, St, Wt);

    k_route7<1><<<B_SZ, 256, 0, stream>>>(lc, sl, Wt, S, St, partial, out);
}